// Round 21
// baseline (873.534 us; speedup 1.0000x reference)
//
#include <hip/hip_runtime.h>

#define S_LEN 577
#define SPAD  640
#define DMODEL 768
#define NH 12
#define DHEAD 64
#define MLPD 3072
#define NROWS (32 * 577)      // 18464
#define MPAD  18688           // 73*256
#define NBH   (32 * 12)       // 384
#define LOG2E 1.44269504088896340736f

typedef __attribute__((ext_vector_type(8))) short s8v;
typedef __attribute__((ext_vector_type(4))) float f4v;

#define MFMA16(a, b, c) __builtin_amdgcn_mfma_f32_16x16x32_bf16((a), (b), (c), 0, 0, 0)

__device__ __forceinline__ short f2bf(float f) {
  union { float f; unsigned u; } a; a.f = f;
  unsigned r = a.u + 0x7FFFu + ((a.u >> 16) & 1u);
  return (short)(r >> 16);
}
// round-half-up bf16 (2 ops)
__device__ __forceinline__ short f2bfF(float f) {
  union { float f; unsigned u; } a; a.f = f;
  return (short)((a.u + 0x8000u) >> 16);
}

__device__ __forceinline__ void gload16(const short* g, const short* l) {
  __builtin_amdgcn_global_load_lds(
      (const __attribute__((address_space(1))) void*)g,
      (__attribute__((address_space(3))) void*)l, 16, 0, 0);
}

// ---------------- prep: transpose fp32 (R,C) -> bf16 (C,R) ----------------
__global__ __launch_bounds__(256) void transpose_w(const float* __restrict__ in,
                                                   short* __restrict__ out, int R, int C) {
  __shared__ float tile[32][33];
  int c0 = blockIdx.x * 32, r0 = blockIdx.y * 32;
  int tx = threadIdx.x, ty = threadIdx.y;
  for (int i = ty; i < 32; i += 8) tile[i][tx] = in[(size_t)(r0 + i) * C + c0 + tx];
  __syncthreads();
  for (int i = ty; i < 32; i += 8) out[(size_t)(c0 + i) * R + r0 + tx] = f2bf(tile[tx][i]);
}

// ---------------- prep: per-head (d,o) -> bf16 (o,d) for wq/wk/wv ----------------
__global__ __launch_bounds__(256) void prep_qkv(const float* __restrict__ wq, const float* __restrict__ wk,
                                                const float* __restrict__ wv, short* __restrict__ oq,
                                                short* __restrict__ ok, short* __restrict__ ov) {
  int h = blockIdx.x, t = threadIdx.x;
  const float* src0 = wq + (size_t)h * 4096;
  const float* src1 = wk + (size_t)h * 4096;
  const float* src2 = wv + (size_t)h * 4096;
  short* dst0 = oq + (size_t)h * 4096;
  short* dst1 = ok + (size_t)h * 4096;
  short* dst2 = ov + (size_t)h * 4096;
  for (int i = t; i < 4096; i += 256) {
    int o = i >> 6, d = i & 63;
    dst0[i] = f2bf(src0[d * 64 + o]);
    dst1[i] = f2bf(src1[d * 64 + o]);
    dst2[i] = f2bf(src2[d * 64 + o]);
  }
}

// ------- zero the s-padding of vt [NBH][64][SPAD] and kg [NBH][SPAD][64], s in [577,640) -------
__global__ __launch_bounds__(256) void pad_kv(short* __restrict__ kg, short* __restrict__ vt) {
  int idx = blockIdx.x * 256 + threadIdx.x;
  const int padw = SPAD - S_LEN;          // 63
  const int per = DHEAD * padw;           // 4032
  if (idx >= NBH * per) return;
  int bh = idx / per, r = idx - bh * per;
  int col = r / padw, s = S_LEN + (r - col * padw);
  vt[((size_t)bh * DHEAD + col) * SPAD + s] = 0;
  kg[((size_t)bh * SPAD + s) * DHEAD + col] = 0;
}

// ---------------- LayerNorm (D=768), fp32 in -> bf16 out ----------------
__global__ __launch_bounds__(256) void ln_kernel(const float* __restrict__ x, const float* __restrict__ g,
                                                 const float* __restrict__ bta, short* __restrict__ out) {
  int row = blockIdx.x;
  int t = threadIdx.x;
  const float* xr = x + (size_t)row * DMODEL;
  float v0 = xr[t], v1 = xr[t + 256], v2 = xr[t + 512];
  float s = v0 + v1 + v2;
  float s2 = v0 * v0 + v1 * v1 + v2 * v2;
  for (int o = 32; o; o >>= 1) { s += __shfl_down(s, o); s2 += __shfl_down(s2, o); }
  __shared__ float red[8];
  if ((t & 63) == 0) { int w = t >> 6; red[w] = s; red[4 + w] = s2; }
  __syncthreads();
  s = red[0] + red[1] + red[2] + red[3];
  s2 = red[4] + red[5] + red[6] + red[7];
  float m = s * (1.f / DMODEL);
  float rs = rsqrtf(s2 * (1.f / DMODEL) - m * m + 1e-5f);
  short* orow = out + (size_t)row * DMODEL;
  orow[t]       = f2bf((v0 - m) * rs * g[t]       + bta[t]);
  orow[t + 256] = f2bf((v1 - m) * rs * g[t + 256] + bta[t + 256]);
  orow[t + 512] = f2bf((v2 - m) * rs * g[t + 512] + bta[t + 512]);
}

// ---------------- QKV: per-head 64x64 GEMM, bias; q pre-scaled (1/8)*log2e; K padded, V transposed ----------------
__global__ __launch_bounds__(256) void qkv_kernel(const short* __restrict__ xn,
    const short* __restrict__ wqt, const short* __restrict__ wkt, const short* __restrict__ wvt,
    const float* __restrict__ bq, const float* __restrict__ bk, const float* __restrict__ bv,
    short* __restrict__ qg, short* __restrict__ kg, short* __restrict__ vt) {
  __shared__ __align__(16) short wl[3][64][72];
  int bid = blockIdx.x;
  int h = bid % NH, mt = bid / NH;
  int t = threadIdx.x;
  {
    int o = t >> 2, d0 = (t & 3) * 16;
    const short* s0 = wqt + (size_t)h * 4096 + o * 64 + d0;
    const short* s1 = wkt + (size_t)h * 4096 + o * 64 + d0;
    const short* s2 = wvt + (size_t)h * 4096 + o * 64 + d0;
    *(uint4*)&wl[0][o][d0]     = *(const uint4*)s0;
    *(uint4*)&wl[0][o][d0 + 8] = *(const uint4*)(s0 + 8);
    *(uint4*)&wl[1][o][d0]     = *(const uint4*)s1;
    *(uint4*)&wl[1][o][d0 + 8] = *(const uint4*)(s1 + 8);
    *(uint4*)&wl[2][o][d0]     = *(const uint4*)s2;
    *(uint4*)&wl[2][o][d0 + 8] = *(const uint4*)(s2 + 8);
  }
  __syncthreads();
  int w = t >> 6, l = t & 63, l15 = l & 15, lh = l >> 4;
  int m0 = mt * 64 + w * 16;
  if (m0 >= NROWS) return;
  f4v z = {0.f, 0.f, 0.f, 0.f};
  f4v aq[4], ak[4], av[4];
#pragma unroll
  for (int nt = 0; nt < 4; ++nt) { aq[nt] = z; ak[nt] = z; av[nt] = z; }
  const short* xrow = xn + (size_t)(m0 + l15) * DMODEL + h * DHEAD;
#pragma unroll
  for (int kk = 0; kk < 64; kk += 32) {
    s8v af = *(const s8v*)(xrow + kk + lh * 8);
#pragma unroll
    for (int nt = 0; nt < 4; ++nt) {
      s8v b0 = *(const s8v*)&wl[0][nt * 16 + l15][kk + lh * 8];
      s8v b1 = *(const s8v*)&wl[1][nt * 16 + l15][kk + lh * 8];
      s8v b2 = *(const s8v*)&wl[2][nt * 16 + l15][kk + lh * 8];
      aq[nt] = MFMA16(af, b0, aq[nt]);
      ak[nt] = MFMA16(af, b1, ak[nt]);
      av[nt] = MFMA16(af, b2, av[nt]);
    }
  }
#pragma unroll
  for (int nt = 0; nt < 4; ++nt) {
    int col = nt * 16 + l15;
    float biq = bq[h * DHEAD + col], bik = bk[h * DHEAD + col], biv = bv[h * DHEAD + col];
#pragma unroll
    for (int i = 0; i < 4; ++i) {
      int m = m0 + lh * 4 + i;
      int bb = m / S_LEN;
      int ss = m - bb * S_LEN;
      int bh = bb * NH + h;
      qg[((size_t)bh * S_LEN + ss) * DHEAD + col] = f2bf((aq[nt][i] + biq) * (0.125f * LOG2E));
      kg[((size_t)bh * SPAD + ss) * DHEAD + col]  = f2bf(ak[nt][i] + bik);
      vt[((size_t)bh * DHEAD + col) * SPAD + ss]  = f2bf(av[nt][i] + biv);
    }
  }
}

// ------- attention: ONE WAVE PER BLOCK, 64 q-rows/wave (4 frags), pipelined, static-max softmax -------
__global__ __launch_bounds__(64, 2) void attn_kernel(const short* __restrict__ qg, const short* __restrict__ kg,
                                                     const short* __restrict__ vt, const float* __restrict__ x,
                                                     float* __restrict__ outp) {
  __shared__ __align__(16) short Pb[2][64][72];      // 18 KB, parity dbuf
  int bh = blockIdx.x;       // 0..383
  int qt = blockIdx.y;       // 0..9
  int h = bh % NH, b = bh / NH;
  int l = threadIdx.x & 63, l15 = l & 15, lh = l >> 4;
  int q0 = qt * 64;
  size_t qbase = (size_t)bh * S_LEN * DHEAD;
  size_t kbase = (size_t)bh * SPAD * DHEAD;
  size_t vbase = (size_t)bh * DHEAD * SPAD;
  s8v aq[4][2];
#pragma unroll
  for (int f = 0; f < 4; ++f) {
    int qrow = q0 + f * 16 + l15; if (qrow > 576) qrow = 576;
    const short* qp = qg + qbase + (size_t)qrow * DHEAD + lh * 8;
    aq[f][0] = *(const s8v*)qp;
    aq[f][1] = *(const s8v*)(qp + 32);
  }
  f4v z = {0.f, 0.f, 0.f, 0.f};
  f4v z16 = {-16.f, -16.f, -16.f, -16.f};   // static-max offset as C-init
  f4v acc[4][4];
  float lsum[4][4];
#pragma unroll
  for (int f = 0; f < 4; ++f) {
#pragma unroll
    for (int dt = 0; dt < 4; ++dt) acc[f][dt] = z;
#pragma unroll
    for (int i = 0; i < 4; ++i) lsum[f][i] = 0.f;
  }

  s8v kf0[4], kf1[4], vf[2][4];
  f4v sc[2][4];

#define LOADK(KB)                                                      \
  {                                                                    \
    _Pragma("unroll")                                                  \
    for (int nt = 0; nt < 4; ++nt) {                                   \
      const short* kp = kg + kbase + (size_t)((KB) + nt * 16 + l15) * DHEAD + lh * 8; \
      kf0[nt] = *(const s8v*)kp;                                       \
      kf1[nt] = *(const s8v*)(kp + 32);                                \
    }                                                                  \
  }

#define LOADV(KB)                                                      \
  {                                                                    \
    _Pragma("unroll")                                                  \
    for (int kk2 = 0; kk2 < 2; ++kk2) {                                \
      const short* vp = vt + vbase + (KB) + kk2 * 32 + lh * 8;         \
      _Pragma("unroll")                                                \
      for (int dt = 0; dt < 4; ++dt)                                   \
        vf[kk2][dt] = *(const s8v*)(vp + (size_t)(dt * 16 + l15) * SPAD); \
    }                                                                  \
  }

// QK for fragment-half FH (f = 2*FH, 2*FH+1) -> sc[0..1]
#define QKT_H(FH)                                                      \
  {                                                                    \
    __builtin_amdgcn_s_setprio(1);                                     \
    _Pragma("unroll")                                                  \
    for (int nt = 0; nt < 4; ++nt) {                                   \
      _Pragma("unroll")                                                \
      for (int fo = 0; fo < 2; ++fo) {                                 \
        f4v a = MFMA16(aq[2 * (FH) + fo][0], kf0[nt], z16);            \
        a = MFMA16(aq[2 * (FH) + fo][1], kf1[nt], a);                  \
        sc[fo][nt] = a;                                                \
      }                                                                \
    }                                                                  \
    __builtin_amdgcn_s_setprio(0);                                     \
  }

// softmax for fragment-half FH; MASK applies the tail-key mask (tile 9)
#define SMAX_H(FH, PAR, MASK)                                          \
  {                                                                    \
    if (MASK) {                                                        \
      _Pragma("unroll")                                                \
      for (int nt = 0; nt < 4; ++nt) {                                 \
        int col = 576 + nt * 16 + l15;                                 \
        if (col > 576) {                                               \
          _Pragma("unroll")                                            \
          for (int fo = 0; fo < 2; ++fo) {                             \
            sc[fo][nt][0] = sc[fo][nt][1] = sc[fo][nt][2] = sc[fo][nt][3] = -1e30f; } \
        }                                                              \
      }                                                                \
    }                                                                  \
    _Pragma("unroll")                                                  \
    for (int fo = 0; fo < 2; ++fo)                                     \
      _Pragma("unroll")                                                \
      for (int i = 0; i < 4; ++i) {                                    \
        float s = lsum[2 * (FH) + fo][i];                              \
        _Pragma("unroll")                                              \
        for (int nt = 0; nt < 4; ++nt) {                               \
          float e = exp2f(sc[fo][nt][i]);                              \
          s += e;                                                      \
          Pb[PAR][(2 * (FH) + fo) * 16 + lh * 4 + i][nt * 16 + l15] = f2bfF(e); \
        }                                                              \
        lsum[2 * (FH) + fo][i] = s;                                    \
      }                                                                \
  }

#define PVT(PAR)                                                       \
  {                                                                    \
    __builtin_amdgcn_s_setprio(1);                                     \
    _Pragma("unroll")                                                  \
    for (int kk2 = 0; kk2 < 2; ++kk2) {                                \
      _Pragma("unroll")                                                \
      for (int f = 0; f < 4; ++f) {                                    \
        s8v af = *(const s8v*)&Pb[PAR][f * 16 + l15][kk2 * 32 + lh * 8]; \
        _Pragma("unroll")                                              \
        for (int dt = 0; dt < 4; ++dt)                                 \
          acc[f][dt] = MFMA16(af, vf[kk2][dt], acc[f][dt]);            \
      }                                                                \
    }                                                                  \
    __builtin_amdgcn_s_setprio(0);                                     \
  }

  // ---- prologue: QK(0)->Pb[0] in two halves; kf refilled after last read ----
  LOADK(0);
  QKT_H(0);
  SMAX_H(0, 0, false);
  QKT_H(1);
  LOADK(64);
  SMAX_H(1, 0, false);

  for (int kt = 0; kt < 10; ++kt) {
    int par = kt & 1;
    LOADV(kt * 64);                        // V(kt), consumed at PVT below
    if (kt < 9) {
      bool mask = (kt == 8);
      QKT_H(0);                            // QK(kt+1) rows 0-31
      SMAX_H(0, par ^ 1, mask);
      QKT_H(1);                            // QK(kt+1) rows 32-63, last read of kf
      if (kt < 8) LOADK((kt + 2) * 64);    // refill kf (used next iter)
      SMAX_H(1, par ^ 1, mask);
    }
    PVT(par);                              // PV(kt) from vf + Pb[par]
  }
#undef LOADK
#undef LOADV
#undef QKT_H
#undef SMAX_H
#undef PVT
  // ---- epilogue: single sum-reduce per row, rcp-normalize + residual ----
#pragma unroll
  for (int f = 0; f < 4; ++f)
#pragma unroll
    for (int i = 0; i < 4; ++i) {
      float s = lsum[f][i];
      s += __shfl_xor(s, 1);
      s += __shfl_xor(s, 2);
      s += __shfl_xor(s, 4);
      s += __shfl_xor(s, 8);
      int srow = q0 + f * 16 + lh * 4 + i;
      if (srow > 576) continue;
      float inv = __builtin_amdgcn_rcpf(s);
      size_t idx0 = ((size_t)b * S_LEN + srow) * DMODEL + h * DHEAD + l15;
#pragma unroll
      for (int dt = 0; dt < 4; ++dt) {
        size_t idx = idx0 + dt * 16;
        outp[idx] = x[idx] + acc[f][dt][i] * inv;
      }
    }
}

// ===== LDS-FREE GEMM: 256 thr / 4 independent waves, each wave a 64x64 output tile =====
// A/B fragments loaded direct global->reg (16B/lane, identical layout to the LDS path).
// B frags are identical across the block's 4 waves (L1 broadcast); no barriers at all.
// Unroll-2 ping-pong gives one-tile register prefetch.
#define GEMMD_BODY                                                                 \
  int nwg = gridDim.x;                                                             \
  int orig = blockIdx.x;                                                           \
  int qq = nwg >> 3, rr = nwg & 7;                                                 \
  int xcd = orig & 7, lin = orig >> 3;                                             \
  int wg = (xcd < rr ? xcd * (qq + 1) : rr * (qq + 1) + (xcd - rr) * qq) + lin;    \
  int nx = N >> 6;                                                                 \
  int n0 = (wg % nx) * 64, mb = (wg / nx) * 256;                                   \
  int tid = threadIdx.x;                                                           \
  int w = tid >> 6, l = tid & 63, l15 = l & 15, lh = l >> 4;                       \
  int m0 = mb + w * 64;                                                            \
  const short* ap[4];                                                              \
  const short* bp[4];                                                              \
  _Pragma("unroll") for (int i = 0; i < 4; ++i) {                                  \
    ap[i] = A  + (size_t)(m0 + i * 16 + l15) * K + lh * 8;                         \
    bp[i] = Bt + (size_t)(n0 + i * 16 + l15) * K + lh * 8;                         \
  }                                                                                \
  f4v z = {0.f, 0.f, 0.f, 0.f};                                                    \
  f4v acc[4][4];                                                                   \
  _Pragma("unroll") for (int i = 0; i < 4; ++i)                                    \
    _Pragma("unroll") for (int j = 0; j < 4; ++j) acc[i][j] = z;                   \
  s8v a0[4], b0[4], a1[4], b1[4];                                                  \
  int NT = K >> 5;                                                                 \
  _Pragma("unroll") for (int i = 0; i < 4; ++i) {                                  \
    a0[i] = *(const s8v*)ap[i];                                                    \
    b0[i] = *(const s8v*)bp[i];                                                    \
  }                                                                                \
  for (int kt = 0; kt < NT; kt += 2) {                                             \
    _Pragma("unroll") for (int i = 0; i < 4; ++i) {                                \
      a1[i] = *(const s8v*)(ap[i] + (kt + 1) * 32);                                \
      b1[i] = *(const s8v*)(bp[i] + (kt + 1) * 32);                                \
    }                                                                              \
    __builtin_amdgcn_s_setprio(1);                                                 \
    _Pragma("unroll") for (int mt = 0; mt < 4; ++mt)                               \
      _Pragma("unroll") for (int nt2 = 0; nt2 < 4; ++nt2)                          \
        acc[mt][nt2] = MFMA16(a0[mt], b0[nt2], acc[mt][nt2]);                      \
    __builtin_amdgcn_s_setprio(0);                                                 \
    if (kt + 2 < NT) {                                                             \
      _Pragma("unroll") for (int i = 0; i < 4; ++i) {                              \
        a0[i] = *(const s8v*)(ap[i] + (kt + 2) * 32);                              \
        b0[i] = *(const s8v*)(bp[i] + (kt + 2) * 32);                              \
      }                                                                            \
    }                                                                              \
    __builtin_amdgcn_s_setprio(1);                                                 \
    _Pragma("unroll") for (int mt = 0; mt < 4; ++mt)                               \
      _Pragma("unroll") for (int nt2 = 0; nt2 < 4; ++nt2)                          \
        acc[mt][nt2] = MFMA16(a1[mt], b1[nt2], acc[mt][nt2]);                      \
    __builtin_amdgcn_s_setprio(0);                                                 \
  }

// ---------------- GEMM + bias + GELU (sigmoid-form, rcp) -> bf16 ----------------
__global__ __launch_bounds__(256) void gemm_gelu(const short* __restrict__ A, const short* __restrict__ Bt,
                                                 const float* __restrict__ bias, short* __restrict__ C,
                                                 int M, int N, int K) {
  GEMMD_BODY
#pragma unroll
  for (int mt = 0; mt < 4; ++mt)
#pragma unroll
    for (int nt2 = 0; nt2 < 4; ++nt2) {
      int col = n0 + nt2 * 16 + l15;
      float bi = bias[col];
#pragma unroll
      for (int i = 0; i < 4; ++i) {
        int row = m0 + mt * 16 + lh * 4 + i;
        float v = acc[mt][nt2][i] + bi;
        float u = v * (2.30221838f + 0.10294364f * v * v);
        v = v * __builtin_amdgcn_rcpf(1.f + exp2f(-u));
        C[(size_t)row * N + col] = f2bfF(v);
      }
    }
}

// ---------------- GEMM + bias + residual (in-place on out) ----------------
__global__ __launch_bounds__(256) void gemm_res(const short* __restrict__ A, const short* __restrict__ Bt,
                                                const float* __restrict__ bias, float* __restrict__ outp,
                                                int Mvalid, int N, int K) {
  GEMMD_BODY
#pragma unroll
  for (int mt = 0; mt < 4; ++mt)
#pragma unroll
    for (int nt2 = 0; nt2 < 4; ++nt2) {
      int col = n0 + nt2 * 16 + l15;
      float bi = bias[col];
#pragma unroll
      for (int i = 0; i < 4; ++i) {
        int row = m0 + mt * 16 + lh * 4 + i;
        if (row < Mvalid) {
          size_t idx = (size_t)row * N + col;
          outp[idx] += acc[mt][nt2][i] + bi;
        }
      }
    }
}

extern "C" void kernel_launch(void* const* d_in, const int* in_sizes, int n_in,
                              void* d_out, int out_size, void* d_ws, size_t ws_size,
                              hipStream_t stream) {
  const float* x    = (const float*)d_in[0];
  const float* ln1g = (const float*)d_in[1];
  const float* ln1b = (const float*)d_in[2];
  const float* ln2g = (const float*)d_in[3];
  const float* ln2b = (const float*)d_in[4];
  const float* wq   = (const float*)d_in[5];
  const float* bq   = (const float*)d_in[6];
  const float* wk   = (const float*)d_in[7];
  const float* bk   = (const float*)d_in[8];
  const float* wv   = (const float*)d_in[9];
  const float* bv   = (const float*)d_in[10];
  const float* w1   = (const float*)d_in[11];
  const float* b1   = (const float*)d_in[12];
  const float* w2   = (const float*)d_in[13];
  const float* b2   = (const float*)d_in[14];
  float* outp = (float*)d_out;

  // ---- workspace layout with aliasing (peak ~158 MiB) ----
  char* ws = (char*)d_ws;
  size_t off = 0;
  auto carve = [&](size_t elems) -> short* {
    short* p = (short*)(ws + off);
    off += elems * sizeof(short);
    off = (off + 255) & ~(size_t)255;
    return p;
  };
  short* yn   = carve((size_t)MPAD * DMODEL);
  short* w1t  = carve((size_t)MLPD * DMODEL);
  short* w2t  = carve((size_t)DMODEL * MLPD);
  short* wqt  = carve((size_t)NH * 64 * 64);
  short* wkt  = carve((size_t)NH * 64 * 64);
  short* wvt  = carve((size_t)NH * 64 * 64);
  size_t union_base = off;
  short* hbuf = carve((size_t)MPAD * MLPD);           // phase B
  off = union_base;                                    // phase A aliases
  short* xn   = carve((size_t)NROWS * DMODEL);
  short* qg   = carve((size_t)NBH * S_LEN * DHEAD);
  short* kg   = carve((size_t)NBH * SPAD * DHEAD);    // K padded to 640 rows
  short* vtb  = carve((size_t)NBH * DHEAD * SPAD);
  (void)ws_size; (void)in_sizes; (void)n_in; (void)out_size;

  // prep weights
  transpose_w<<<dim3(MLPD / 32, DMODEL / 32), dim3(32, 8), 0, stream>>>(w1, w1t, DMODEL, MLPD);
  transpose_w<<<dim3(DMODEL / 32, MLPD / 32), dim3(32, 8), 0, stream>>>(w2, w2t, MLPD, DMODEL);
  prep_qkv<<<NH, 256, 0, stream>>>(wq, wk, wv, wqt, wkt, wvt);
  pad_kv<<<(NBH * DHEAD * (SPAD - S_LEN) + 255) / 256, 256, 0, stream>>>(kg, vtb);

  // LN1 -> xn (bf16)
  ln_kernel<<<NROWS, 256, 0, stream>>>(x, ln1g, ln1b, xn);

  // QKV projections (K padded rows, V transposed)
  qkv_kernel<<<((NROWS + 63) / 64) * NH, 256, 0, stream>>>(xn, wqt, wkt, wvt, bq, bk, bv, qg, kg, vtb);

  // attention + residual1 -> d_out (1-wave blocks, 64 q-rows each)
  attn_kernel<<<dim3(NBH, 10), 64, 0, stream>>>(qg, kg, vtb, x, outp);

  // LN2 -> yn
  ln_kernel<<<NROWS, 256, 0, stream>>>(outp, ln2g, ln2b, yn);

  // MLP (LDS-free direct-to-reg GEMMs; 1-D grids, XCD-chunked, n-fastest for A L2 reuse)
  gemm_gelu<<<dim3((MPAD / 256) * (MLPD / 64)), 256, 0, stream>>>(yn, w1t, b1, hbuf, MPAD, MLPD, DMODEL);
  gemm_res<<<dim3((MPAD / 256) * (DMODEL / 64)), 256, 0, stream>>>(hbuf, w2t, b2, outp, NROWS, DMODEL, MLPD);
}

// Round 22
// 432.404 us; speedup vs baseline: 2.0202x; 2.0202x over previous
//
#include <hip/hip_runtime.h>

#define S_LEN 577
#define SPAD  640
#define DMODEL 768
#define NH 12
#define DHEAD 64
#define MLPD 3072
#define NROWS (32 * 577)      // 18464
#define MPAD  18688           // 146*128
#define NBH   (32 * 12)       // 384
#define LOG2E 1.44269504088896340736f

typedef __attribute__((ext_vector_type(8))) short s8v;
typedef __attribute__((ext_vector_type(4))) float f4v;

#define MFMA16(a, b, c) __builtin_amdgcn_mfma_f32_16x16x32_bf16((a), (b), (c), 0, 0, 0)

__device__ __forceinline__ short f2bf(float f) {
  union { float f; unsigned u; } a; a.f = f;
  unsigned r = a.u + 0x7FFFu + ((a.u >> 16) & 1u);
  return (short)(r >> 16);
}
// round-half-up bf16 (2 ops)
__device__ __forceinline__ short f2bfF(float f) {
  union { float f; unsigned u; } a; a.f = f;
  return (short)((a.u + 0x8000u) >> 16);
}

__device__ __forceinline__ void gload16(const short* g, const short* l) {
  __builtin_amdgcn_global_load_lds(
      (const __attribute__((address_space(1))) void*)g,
      (__attribute__((address_space(3))) void*)l, 16, 0, 0);
}

// ---------------- prep: transpose fp32 (R,C) -> bf16 (C,R) ----------------
__global__ __launch_bounds__(256) void transpose_w(const float* __restrict__ in,
                                                   short* __restrict__ out, int R, int C) {
  __shared__ float tile[32][33];
  int c0 = blockIdx.x * 32, r0 = blockIdx.y * 32;
  int tx = threadIdx.x, ty = threadIdx.y;
  for (int i = ty; i < 32; i += 8) tile[i][tx] = in[(size_t)(r0 + i) * C + c0 + tx];
  __syncthreads();
  for (int i = ty; i < 32; i += 8) out[(size_t)(c0 + i) * R + r0 + tx] = f2bf(tile[tx][i]);
}

// ---------------- prep: per-head (d,o) -> bf16 (o,d) for wq/wk/wv ----------------
__global__ __launch_bounds__(256) void prep_qkv(const float* __restrict__ wq, const float* __restrict__ wk,
                                                const float* __restrict__ wv, short* __restrict__ oq,
                                                short* __restrict__ ok, short* __restrict__ ov) {
  int h = blockIdx.x, t = threadIdx.x;
  const float* src0 = wq + (size_t)h * 4096;
  const float* src1 = wk + (size_t)h * 4096;
  const float* src2 = wv + (size_t)h * 4096;
  short* dst0 = oq + (size_t)h * 4096;
  short* dst1 = ok + (size_t)h * 4096;
  short* dst2 = ov + (size_t)h * 4096;
  for (int i = t; i < 4096; i += 256) {
    int o = i >> 6, d = i & 63;
    dst0[i] = f2bf(src0[d * 64 + o]);
    dst1[i] = f2bf(src1[d * 64 + o]);
    dst2[i] = f2bf(src2[d * 64 + o]);
  }
}

// ------- zero the s-padding of vt [NBH][64][SPAD] and kg [NBH][SPAD][64], s in [577,640) -------
__global__ __launch_bounds__(256) void pad_kv(short* __restrict__ kg, short* __restrict__ vt) {
  int idx = blockIdx.x * 256 + threadIdx.x;
  const int padw = SPAD - S_LEN;          // 63
  const int per = DHEAD * padw;           // 4032
  if (idx >= NBH * per) return;
  int bh = idx / per, r = idx - bh * per;
  int col = r / padw, s = S_LEN + (r - col * padw);
  vt[((size_t)bh * DHEAD + col) * SPAD + s] = 0;
  kg[((size_t)bh * SPAD + s) * DHEAD + col] = 0;
}

// ---------------- LayerNorm (D=768), fp32 in -> bf16 out ----------------
__global__ __launch_bounds__(256) void ln_kernel(const float* __restrict__ x, const float* __restrict__ g,
                                                 const float* __restrict__ bta, short* __restrict__ out) {
  int row = blockIdx.x;
  int t = threadIdx.x;
  const float* xr = x + (size_t)row * DMODEL;
  float v0 = xr[t], v1 = xr[t + 256], v2 = xr[t + 512];
  float s = v0 + v1 + v2;
  float s2 = v0 * v0 + v1 * v1 + v2 * v2;
  for (int o = 32; o; o >>= 1) { s += __shfl_down(s, o); s2 += __shfl_down(s2, o); }
  __shared__ float red[8];
  if ((t & 63) == 0) { int w = t >> 6; red[w] = s; red[4 + w] = s2; }
  __syncthreads();
  s = red[0] + red[1] + red[2] + red[3];
  s2 = red[4] + red[5] + red[6] + red[7];
  float m = s * (1.f / DMODEL);
  float rs = rsqrtf(s2 * (1.f / DMODEL) - m * m + 1e-5f);
  short* orow = out + (size_t)row * DMODEL;
  orow[t]       = f2bf((v0 - m) * rs * g[t]       + bta[t]);
  orow[t + 256] = f2bf((v1 - m) * rs * g[t + 256] + bta[t + 256]);
  orow[t + 512] = f2bf((v2 - m) * rs * g[t + 512] + bta[t + 512]);
}

// ---------------- QKV: per-head 64x64 GEMM, bias; q pre-scaled (1/8)*log2e; K padded, V transposed ----------------
__global__ __launch_bounds__(256) void qkv_kernel(const short* __restrict__ xn,
    const short* __restrict__ wqt, const short* __restrict__ wkt, const short* __restrict__ wvt,
    const float* __restrict__ bq, const float* __restrict__ bk, const float* __restrict__ bv,
    short* __restrict__ qg, short* __restrict__ kg, short* __restrict__ vt) {
  __shared__ __align__(16) short wl[3][64][72];
  int bid = blockIdx.x;
  int h = bid % NH, mt = bid / NH;
  int t = threadIdx.x;
  {
    int o = t >> 2, d0 = (t & 3) * 16;
    const short* s0 = wqt + (size_t)h * 4096 + o * 64 + d0;
    const short* s1 = wkt + (size_t)h * 4096 + o * 64 + d0;
    const short* s2 = wvt + (size_t)h * 4096 + o * 64 + d0;
    *(uint4*)&wl[0][o][d0]     = *(const uint4*)s0;
    *(uint4*)&wl[0][o][d0 + 8] = *(const uint4*)(s0 + 8);
    *(uint4*)&wl[1][o][d0]     = *(const uint4*)s1;
    *(uint4*)&wl[1][o][d0 + 8] = *(const uint4*)(s1 + 8);
    *(uint4*)&wl[2][o][d0]     = *(const uint4*)s2;
    *(uint4*)&wl[2][o][d0 + 8] = *(const uint4*)(s2 + 8);
  }
  __syncthreads();
  int w = t >> 6, l = t & 63, l15 = l & 15, lh = l >> 4;
  int m0 = mt * 64 + w * 16;
  if (m0 >= NROWS) return;
  f4v z = {0.f, 0.f, 0.f, 0.f};
  f4v aq[4], ak[4], av[4];
#pragma unroll
  for (int nt = 0; nt < 4; ++nt) { aq[nt] = z; ak[nt] = z; av[nt] = z; }
  const short* xrow = xn + (size_t)(m0 + l15) * DMODEL + h * DHEAD;
#pragma unroll
  for (int kk = 0; kk < 64; kk += 32) {
    s8v af = *(const s8v*)(xrow + kk + lh * 8);
#pragma unroll
    for (int nt = 0; nt < 4; ++nt) {
      s8v b0 = *(const s8v*)&wl[0][nt * 16 + l15][kk + lh * 8];
      s8v b1 = *(const s8v*)&wl[1][nt * 16 + l15][kk + lh * 8];
      s8v b2 = *(const s8v*)&wl[2][nt * 16 + l15][kk + lh * 8];
      aq[nt] = MFMA16(af, b0, aq[nt]);
      ak[nt] = MFMA16(af, b1, ak[nt]);
      av[nt] = MFMA16(af, b2, av[nt]);
    }
  }
#pragma unroll
  for (int nt = 0; nt < 4; ++nt) {
    int col = nt * 16 + l15;
    float biq = bq[h * DHEAD + col], bik = bk[h * DHEAD + col], biv = bv[h * DHEAD + col];
#pragma unroll
    for (int i = 0; i < 4; ++i) {
      int m = m0 + lh * 4 + i;
      int bb = m / S_LEN;
      int ss = m - bb * S_LEN;
      int bh = bb * NH + h;
      qg[((size_t)bh * S_LEN + ss) * DHEAD + col] = f2bf((aq[nt][i] + biq) * (0.125f * LOG2E));
      kg[((size_t)bh * SPAD + ss) * DHEAD + col]  = f2bf(ak[nt][i] + bik);
      vt[((size_t)bh * DHEAD + col) * SPAD + ss]  = f2bf(av[nt][i] + biv);
    }
  }
}

// ------- attention: ONE WAVE PER BLOCK, 64 q-rows/wave (4 frags), pipelined, static-max softmax -------
__global__ __launch_bounds__(64, 2) void attn_kernel(const short* __restrict__ qg, const short* __restrict__ kg,
                                                     const short* __restrict__ vt, const float* __restrict__ x,
                                                     float* __restrict__ outp) {
  __shared__ __align__(16) short Pb[2][64][72];      // 18 KB, parity dbuf
  int bh = blockIdx.x;       // 0..383
  int qt = blockIdx.y;       // 0..9
  int h = bh % NH, b = bh / NH;
  int l = threadIdx.x & 63, l15 = l & 15, lh = l >> 4;
  int q0 = qt * 64;
  size_t qbase = (size_t)bh * S_LEN * DHEAD;
  size_t kbase = (size_t)bh * SPAD * DHEAD;
  size_t vbase = (size_t)bh * DHEAD * SPAD;
  s8v aq[4][2];
#pragma unroll
  for (int f = 0; f < 4; ++f) {
    int qrow = q0 + f * 16 + l15; if (qrow > 576) qrow = 576;
    const short* qp = qg + qbase + (size_t)qrow * DHEAD + lh * 8;
    aq[f][0] = *(const s8v*)qp;
    aq[f][1] = *(const s8v*)(qp + 32);
  }
  f4v z = {0.f, 0.f, 0.f, 0.f};
  f4v z16 = {-16.f, -16.f, -16.f, -16.f};   // static-max offset as C-init
  f4v acc[4][4];
  float lsum[4][4];
#pragma unroll
  for (int f = 0; f < 4; ++f) {
#pragma unroll
    for (int dt = 0; dt < 4; ++dt) acc[f][dt] = z;
#pragma unroll
    for (int i = 0; i < 4; ++i) lsum[f][i] = 0.f;
  }

  s8v kf0[4], kf1[4], vf[2][4];
  f4v sc[2][4];

#define LOADK(KB)                                                      \
  {                                                                    \
    _Pragma("unroll")                                                  \
    for (int nt = 0; nt < 4; ++nt) {                                   \
      const short* kp = kg + kbase + (size_t)((KB) + nt * 16 + l15) * DHEAD + lh * 8; \
      kf0[nt] = *(const s8v*)kp;                                       \
      kf1[nt] = *(const s8v*)(kp + 32);                                \
    }                                                                  \
  }

#define LOADV(KB)                                                      \
  {                                                                    \
    _Pragma("unroll")                                                  \
    for (int kk2 = 0; kk2 < 2; ++kk2) {                                \
      const short* vp = vt + vbase + (KB) + kk2 * 32 + lh * 8;         \
      _Pragma("unroll")                                                \
      for (int dt = 0; dt < 4; ++dt)                                   \
        vf[kk2][dt] = *(const s8v*)(vp + (size_t)(dt * 16 + l15) * SPAD); \
    }                                                                  \
  }

// QK for fragment-half FH (f = 2*FH, 2*FH+1) -> sc[0..1]
#define QKT_H(FH)                                                      \
  {                                                                    \
    __builtin_amdgcn_s_setprio(1);                                     \
    _Pragma("unroll")                                                  \
    for (int nt = 0; nt < 4; ++nt) {                                   \
      _Pragma("unroll")                                                \
      for (int fo = 0; fo < 2; ++fo) {                                 \
        f4v a = MFMA16(aq[2 * (FH) + fo][0], kf0[nt], z16);            \
        a = MFMA16(aq[2 * (FH) + fo][1], kf1[nt], a);                  \
        sc[fo][nt] = a;                                                \
      }                                                                \
    }                                                                  \
    __builtin_amdgcn_s_setprio(0);                                     \
  }

// softmax for fragment-half FH; MASK applies the tail-key mask (tile 9)
#define SMAX_H(FH, PAR, MASK)                                          \
  {                                                                    \
    if (MASK) {                                                        \
      _Pragma("unroll")                                                \
      for (int nt = 0; nt < 4; ++nt) {                                 \
        int col = 576 + nt * 16 + l15;                                 \
        if (col > 576) {                                               \
          _Pragma("unroll")                                            \
          for (int fo = 0; fo < 2; ++fo) {                             \
            sc[fo][nt][0] = sc[fo][nt][1] = sc[fo][nt][2] = sc[fo][nt][3] = -1e30f; } \
        }                                                              \
      }                                                                \
    }                                                                  \
    _Pragma("unroll")                                                  \
    for (int fo = 0; fo < 2; ++fo)                                     \
      _Pragma("unroll")                                                \
      for (int i = 0; i < 4; ++i) {                                    \
        float s = lsum[2 * (FH) + fo][i];                              \
        _Pragma("unroll")                                              \
        for (int nt = 0; nt < 4; ++nt) {                               \
          float e = exp2f(sc[fo][nt][i]);                              \
          s += e;                                                      \
          Pb[PAR][(2 * (FH) + fo) * 16 + lh * 4 + i][nt * 16 + l15] = f2bfF(e); \
        }                                                              \
        lsum[2 * (FH) + fo][i] = s;                                    \
      }                                                                \
  }

#define PVT(PAR)                                                       \
  {                                                                    \
    __builtin_amdgcn_s_setprio(1);                                     \
    _Pragma("unroll")                                                  \
    for (int kk2 = 0; kk2 < 2; ++kk2) {                                \
      _Pragma("unroll")                                                \
      for (int f = 0; f < 4; ++f) {                                    \
        s8v af = *(const s8v*)&Pb[PAR][f * 16 + l15][kk2 * 32 + lh * 8]; \
        _Pragma("unroll")                                              \
        for (int dt = 0; dt < 4; ++dt)                                 \
          acc[f][dt] = MFMA16(af, vf[kk2][dt], acc[f][dt]);            \
      }                                                                \
    }                                                                  \
    __builtin_amdgcn_s_setprio(0);                                     \
  }

  // ---- prologue: QK(0)->Pb[0] in two halves; kf refilled after last read ----
  LOADK(0);
  QKT_H(0);
  SMAX_H(0, 0, false);
  QKT_H(1);
  LOADK(64);
  SMAX_H(1, 0, false);

  for (int kt = 0; kt < 10; ++kt) {
    int par = kt & 1;
    LOADV(kt * 64);                        // V(kt), consumed at PVT below
    if (kt < 9) {
      bool mask = (kt == 8);
      QKT_H(0);                            // QK(kt+1) rows 0-31
      SMAX_H(0, par ^ 1, mask);
      QKT_H(1);                            // QK(kt+1) rows 32-63, last read of kf
      if (kt < 8) LOADK((kt + 2) * 64);    // refill kf (used next iter)
      SMAX_H(1, par ^ 1, mask);
    }
    PVT(par);                              // PV(kt) from vf + Pb[par]
  }
#undef LOADK
#undef LOADV
#undef QKT_H
#undef SMAX_H
#undef PVT
  // ---- epilogue: single sum-reduce per row, rcp-normalize + residual ----
#pragma unroll
  for (int f = 0; f < 4; ++f)
#pragma unroll
    for (int i = 0; i < 4; ++i) {
      float s = lsum[f][i];
      s += __shfl_xor(s, 1);
      s += __shfl_xor(s, 2);
      s += __shfl_xor(s, 4);
      s += __shfl_xor(s, 8);
      int srow = q0 + f * 16 + lh * 4 + i;
      if (srow > 576) continue;
      float inv = __builtin_amdgcn_rcpf(s);
      size_t idx0 = ((size_t)b * S_LEN + srow) * DMODEL + h * DHEAD + l15;
#pragma unroll
      for (int dt = 0; dt < 4; ++dt) {
        size_t idx = idx0 + dt * 16;
        outp[idx] = x[idx] + acc[f][dt][i] * inv;
      }
    }
}

// ===== 128x256 GEMM, 512 thr (8 waves: 2 M-rows x 4 N-cols of 64x64), BK=32, dbuf 48KB LDS =====
// Per K-tile: __syncthreads (drains last iter's stage) -> stage kt+1 (3 gload16/thr) ->
// 8 ds_read -> 16 MFMA. Read swizzle slot^=(row>>1)&3 with inverse-swizzled global source.
#define GEMM128_BODY                                                               \
  int nwg = gridDim.x;                                                             \
  int orig = blockIdx.x;                                                           \
  int qq = nwg >> 3, rr = nwg & 7;                                                 \
  int xcd = orig & 7, lin = orig >> 3;                                             \
  int wg = (xcd < rr ? xcd * (qq + 1) : rr * (qq + 1) + (xcd - rr) * qq) + lin;    \
  int nx = N >> 8;                                                                 \
  int n0 = (wg % nx) * 256, m0 = (wg / nx) * 128;                                  \
  int tid = threadIdx.x;                                                           \
  int wid = tid >> 6, l = tid & 63, l15 = l & 15, lh = l >> 4;                     \
  int wr = wid >> 2, wc = wid & 3;                                                 \
  int srow = tid >> 2, sslot = tid & 3;                                            \
  int scol = (sslot ^ ((srow >> 1) & 3)) * 8;  /* (srow+128)>>1 has same &3 */     \
  const short* Ab = A + (size_t)m0 * K;                                            \
  const short* Bb = Bt + (size_t)n0 * K;                                           \
  f4v z = {0.f, 0.f, 0.f, 0.f};                                                    \
  f4v acc[4][4];                                                                   \
  _Pragma("unroll") for (int i = 0; i < 4; ++i)                                    \
    _Pragma("unroll") for (int j = 0; j < 4; ++j) acc[i][j] = z;                   \
  s8v af[4], bf[4];                                                                \
  int NT = K >> 5;                                                                 \
  gload16(Ab + (size_t)srow * K + scol, &sA[0][srow][sslot * 8]);                  \
  gload16(Bb + (size_t)srow * K + scol, &sB[0][srow][sslot * 8]);                  \
  gload16(Bb + (size_t)(srow + 128) * K + scol, &sB[0][srow + 128][sslot * 8]);    \
  int cur = 0;                                                                     \
  for (int kt = 0; kt < NT; ++kt) {                                                \
    __syncthreads();                                                               \
    if (kt + 1 < NT) {                                                             \
      size_t ko = (size_t)(kt + 1) * 32 + scol;                                    \
      gload16(Ab + (size_t)srow * K + ko, &sA[cur ^ 1][srow][sslot * 8]);          \
      gload16(Bb + (size_t)srow * K + ko, &sB[cur ^ 1][srow][sslot * 8]);          \
      gload16(Bb + (size_t)(srow + 128) * K + ko, &sB[cur ^ 1][srow + 128][sslot * 8]); \
    }                                                                              \
    _Pragma("unroll") for (int mt = 0; mt < 4; ++mt) {                             \
      int r_ = wr * 64 + mt * 16 + l15;                                            \
      af[mt] = *(const s8v*)&sA[cur][r_][(lh ^ ((r_ >> 1) & 3)) * 8];              \
    }                                                                              \
    _Pragma("unroll") for (int nt2 = 0; nt2 < 4; ++nt2) {                          \
      int r_ = wc * 64 + nt2 * 16 + l15;                                           \
      bf[nt2] = *(const s8v*)&sB[cur][r_][(lh ^ ((r_ >> 1) & 3)) * 8];             \
    }                                                                              \
    __builtin_amdgcn_s_setprio(1);                                                 \
    _Pragma("unroll") for (int mt = 0; mt < 4; ++mt)                               \
      _Pragma("unroll") for (int nt2 = 0; nt2 < 4; ++nt2)                          \
        acc[mt][nt2] = MFMA16(af[mt], bf[nt2], acc[mt][nt2]);                      \
    __builtin_amdgcn_s_setprio(0);                                                 \
    cur ^= 1;                                                                      \
  }

// ---------------- 128x256 GEMM + bias + GELU (sigmoid-form, rcp) -> bf16 ----------------
__global__ __launch_bounds__(512) void gemm_gelu(const short* __restrict__ A, const short* __restrict__ Bt,
                                                 const float* __restrict__ bias, short* __restrict__ C,
                                                 int M, int N, int K) {
  __shared__ __align__(16) short sA[2][128][32];
  __shared__ __align__(16) short sB[2][256][32];
  GEMM128_BODY
#pragma unroll
  for (int mt = 0; mt < 4; ++mt)
#pragma unroll
    for (int nt2 = 0; nt2 < 4; ++nt2) {
      int col = n0 + wc * 64 + nt2 * 16 + l15;
      float bi = bias[col];
#pragma unroll
      for (int i = 0; i < 4; ++i) {
        int row = m0 + wr * 64 + mt * 16 + lh * 4 + i;
        float v = acc[mt][nt2][i] + bi;
        float u = v * (2.30221838f + 0.10294364f * v * v);
        v = v * __builtin_amdgcn_rcpf(1.f + exp2f(-u));
        C[(size_t)row * N + col] = f2bfF(v);
      }
    }
}

// ---------------- 128x256 GEMM + bias + residual (in-place on out) ----------------
__global__ __launch_bounds__(512) void gemm_res(const short* __restrict__ A, const short* __restrict__ Bt,
                                                const float* __restrict__ bias, float* __restrict__ outp,
                                                int Mvalid, int N, int K) {
  __shared__ __align__(16) short sA[2][128][32];
  __shared__ __align__(16) short sB[2][256][32];
  GEMM128_BODY
#pragma unroll
  for (int mt = 0; mt < 4; ++mt)
#pragma unroll
    for (int nt2 = 0; nt2 < 4; ++nt2) {
      int col = n0 + wc * 64 + nt2 * 16 + l15;
      float bi = bias[col];
#pragma unroll
      for (int i = 0; i < 4; ++i) {
        int row = m0 + wr * 64 + mt * 16 + lh * 4 + i;
        if (row < Mvalid) {
          size_t idx = (size_t)row * N + col;
          outp[idx] += acc[mt][nt2][i] + bi;
        }
      }
    }
}

extern "C" void kernel_launch(void* const* d_in, const int* in_sizes, int n_in,
                              void* d_out, int out_size, void* d_ws, size_t ws_size,
                              hipStream_t stream) {
  const float* x    = (const float*)d_in[0];
  const float* ln1g = (const float*)d_in[1];
  const float* ln1b = (const float*)d_in[2];
  const float* ln2g = (const float*)d_in[3];
  const float* ln2b = (const float*)d_in[4];
  const float* wq   = (const float*)d_in[5];
  const float* bq   = (const float*)d_in[6];
  const float* wk   = (const float*)d_in[7];
  const float* bk   = (const float*)d_in[8];
  const float* wv   = (const float*)d_in[9];
  const float* bv   = (const float*)d_in[10];
  const float* w1   = (const float*)d_in[11];
  const float* b1   = (const float*)d_in[12];
  const float* w2   = (const float*)d_in[13];
  const float* b2   = (const float*)d_in[14];
  float* outp = (float*)d_out;

  // ---- workspace layout with aliasing (peak ~158 MiB) ----
  char* ws = (char*)d_ws;
  size_t off = 0;
  auto carve = [&](size_t elems) -> short* {
    short* p = (short*)(ws + off);
    off += elems * sizeof(short);
    off = (off + 255) & ~(size_t)255;
    return p;
  };
  short* yn   = carve((size_t)MPAD * DMODEL);
  short* w1t  = carve((size_t)MLPD * DMODEL);
  short* w2t  = carve((size_t)DMODEL * MLPD);
  short* wqt  = carve((size_t)NH * 64 * 64);
  short* wkt  = carve((size_t)NH * 64 * 64);
  short* wvt  = carve((size_t)NH * 64 * 64);
  size_t union_base = off;
  short* hbuf = carve((size_t)MPAD * MLPD);           // phase B
  off = union_base;                                    // phase A aliases
  short* xn   = carve((size_t)NROWS * DMODEL);
  short* qg   = carve((size_t)NBH * S_LEN * DHEAD);
  short* kg   = carve((size_t)NBH * SPAD * DHEAD);    // K padded to 640 rows
  short* vtb  = carve((size_t)NBH * DHEAD * SPAD);
  (void)ws_size; (void)in_sizes; (void)n_in; (void)out_size;

  // prep weights
  transpose_w<<<dim3(MLPD / 32, DMODEL / 32), dim3(32, 8), 0, stream>>>(w1, w1t, DMODEL, MLPD);
  transpose_w<<<dim3(DMODEL / 32, MLPD / 32), dim3(32, 8), 0, stream>>>(w2, w2t, MLPD, DMODEL);
  prep_qkv<<<NH, 256, 0, stream>>>(wq, wk, wv, wqt, wkt, wvt);
  pad_kv<<<(NBH * DHEAD * (SPAD - S_LEN) + 255) / 256, 256, 0, stream>>>(kg, vtb);

  // LN1 -> xn (bf16)
  ln_kernel<<<NROWS, 256, 0, stream>>>(x, ln1g, ln1b, xn);

  // QKV projections (K padded rows, V transposed)
  qkv_kernel<<<((NROWS + 63) / 64) * NH, 256, 0, stream>>>(xn, wqt, wkt, wvt, bq, bk, bv, qg, kg, vtb);

  // attention + residual1 -> d_out (1-wave blocks, 64 q-rows each)
  attn_kernel<<<dim3(NBH, 10), 64, 0, stream>>>(qg, kg, vtb, x, outp);

  // LN2 -> yn
  ln_kernel<<<NROWS, 256, 0, stream>>>(outp, ln2g, ln2b, yn);

  // MLP (128x256 BK=32 dbuf kernels, 512 threads; 1-D grids, XCD-chunked inside)
  gemm_gelu<<<dim3((MPAD / 128) * (MLPD / 256)), 512, 0, stream>>>(yn, w1t, b1, hbuf, MPAD, MLPD, DMODEL);
  gemm_res<<<dim3((MPAD / 128) * (DMODEL / 256)), 512, 0, stream>>>(hbuf, w2t, b2, outp, NROWS, DMODEL, MLPD);
}